// Round 1
// baseline (316.110 us; speedup 1.0000x reference)
//
#include <hip/hip_runtime.h>

// Correlation / cost-volume (kernel_size=1, stride=1, max_disp=4).
// out[b, dy*9+dx, y, x] = (1/C) * sum_c in1[b,c,y,x] * in2[b,c,y+dy-4,x+dx-4]
// B=8 C=192 H=W=128, fp32. No fp32 MFMA on CDNA4 -> vector-ALU kernel.

constexpr int MAXD = 4;
constexpr int WIN  = 2 * MAXD + 1;   // 9
constexpr int Bn = 8, Cn = 192, Hn = 128, Wn = 128;

constexpr int XT = 16;               // x tile per block
constexpr int YT = 16;               // y tile per block
constexpr int XR = 4;                // x pixels per thread
constexpr int W2 = XT + 2 * MAXD;    // 24 (in2 tile width incl. halo)
constexpr int H2 = YT + 2 * MAXD;    // 24
constexpr int CC = 8;                // channels staged per barrier interval
constexpr int NTHREADS = (XT / XR) * YT * WIN;  // 4*16*9 = 576 (9 waves)
constexpr int CHUNKS = CC * H2 * (W2 / 4);       // 8*24*6 = 1152 16B chunks
constexpr int CHUNKS_PER_THREAD = CHUNKS / NTHREADS;  // 2

__global__ __launch_bounds__(NTHREADS)
void corr_kernel(const float* __restrict__ in1,
                 const float* __restrict__ in2,
                 float* __restrict__ out)
{
    __shared__ float s2[CC * H2 * W2];   // 18,432 B

    const int tid = threadIdx.x;
    const int tx  = tid & 3;           // 0..3  (x group)
    const int ty  = (tid >> 2) & 15;   // 0..15 (y)
    const int g   = tid >> 6;          // 0..8  (wave id == dy)

    const int x0 = blockIdx.x * XT;
    const int y0 = blockIdx.y * YT;
    const int b  = blockIdx.z;

    const int x = x0 + tx * XR;
    const int y = y0 + ty;

    float acc[WIN][XR];
    #pragma unroll
    for (int dx = 0; dx < WIN; ++dx)
        #pragma unroll
        for (int i = 0; i < XR; ++i) acc[dx][i] = 0.f;

    const float* in1p = in1 + (((size_t)b * Cn) * Hn + y) * Wn + x;
    const float* in2b = in2 + ((size_t)b * Cn) * Hn * Wn;

    for (int c0 = 0; c0 < Cn; c0 += CC) {
        __syncthreads();
        // ---- stage CC channels of the in2 halo tile into LDS (zero-padded) ----
        #pragma unroll
        for (int j = 0; j < CHUNKS_PER_THREAD; ++j) {
            int chunk = tid + j * NTHREADS;          // 0..1151
            int k   = chunk % 6;                     // 16B chunk within row
            int row = (chunk / 6) % H2;              // 0..23
            int c   = chunk / (6 * H2);              // 0..7
            int gy  = y0 - MAXD + row;
            int gxf = x0 - MAXD + k * 4;
            float4 v;
            if (gy >= 0 && gy < Hn && gxf >= 0 && gxf + 4 <= Wn) {
                v = *(const float4*)(in2b + ((size_t)(c0 + c) * Hn + gy) * Wn + gxf);
            } else {
                v.x = v.y = v.z = v.w = 0.f;
                if (gy >= 0 && gy < Hn) {
                    const float* rp = in2b + ((size_t)(c0 + c) * Hn + gy) * Wn;
                    if (gxf + 0 >= 0 && gxf + 0 < Wn) v.x = rp[gxf + 0];
                    if (gxf + 1 >= 0 && gxf + 1 < Wn) v.y = rp[gxf + 1];
                    if (gxf + 2 >= 0 && gxf + 2 < Wn) v.z = rp[gxf + 2];
                    if (gxf + 3 >= 0 && gxf + 3 < Wn) v.w = rp[gxf + 3];
                }
            }
            *(float4*)&s2[(c * H2 + row) * W2 + k * 4] = v;
        }
        __syncthreads();

        // ---- compute: each thread = 4 x-pixels, dy = g, all 9 dx ----
        #pragma unroll
        for (int cc = 0; cc < CC; ++cc) {
            float4 a1 = *(const float4*)(in1p + (size_t)(c0 + cc) * Hn * Wn);
            const float* rowp = &s2[(cc * H2 + ty + g) * W2 + tx * XR];
            float f[12];
            *(float4*)&f[0] = *(const float4*)(rowp);
            *(float4*)&f[4] = *(const float4*)(rowp + 4);
            *(float4*)&f[8] = *(const float4*)(rowp + 8);
            #pragma unroll
            for (int dx = 0; dx < WIN; ++dx) {
                acc[dx][0] += a1.x * f[dx + 0];
                acc[dx][1] += a1.y * f[dx + 1];
                acc[dx][2] += a1.z * f[dx + 2];
                acc[dx][3] += a1.w * f[dx + 3];
            }
        }
    }

    const float scale = 1.0f / (float)Cn;
    #pragma unroll
    for (int dx = 0; dx < WIN; ++dx) {
        int d = g * WIN + dx;
        float4 v = { acc[dx][0] * scale, acc[dx][1] * scale,
                     acc[dx][2] * scale, acc[dx][3] * scale };
        *(float4*)(out + (((size_t)b * (WIN * WIN) + d) * Hn + y) * Wn + x) = v;
    }
}

extern "C" void kernel_launch(void* const* d_in, const int* in_sizes, int n_in,
                              void* d_out, int out_size, void* d_ws, size_t ws_size,
                              hipStream_t stream) {
    const float* in1 = (const float*)d_in[0];
    const float* in2 = (const float*)d_in[1];
    float* out = (float*)d_out;
    dim3 grid(Wn / XT, Hn / YT, Bn);
    corr_kernel<<<grid, NTHREADS, 0, stream>>>(in1, in2, out);
}